// Round 10
// baseline (166.940 us; speedup 1.0000x reference)
//
#include <hip/hip_runtime.h>

#define MAXIT  100
#define TARGET 30.0f
#define WEIGHT 0.1f
#define EPS    1e-6f
#define EPB    1024    // elements per block
#define TPB    256
#define R0     12      // phase-A iters (3 bodies of 4, from z=0)
#define RSTEP  12      // iters per queue round (3 bodies of 4)
#define ND_INSET ((100.0f - TARGET) * (1.0f / TARGET))
#define INV_T  (1.0f / TARGET)

typedef float f32x2 __attribute__((ext_vector_type(2)));

__device__ __forceinline__ f32x2 pkfma(f32x2 a, f32x2 b, f32x2 c) {
  return __builtin_elementwise_fma(a, b, c);   // -> v_pk_fma_f32 on gfx950
}

// Scalar replay of one body4 from its entry state; returns the exact retire
// value. Op order mirrors the packed body bit-exactly (v_pk_fma_f32 halves
// are IEEE-identical to v_fma_f32), so the trigger reproduces precisely.
// Precedence: earlier escape > cycle-at-step-4 > escape-at-step-4; clamp 100.
__device__ float decode4(float zr, float zi, float cr, float ci, float fb) {
  float t0  = __builtin_fmaf(-zi, zi, cr);
  float zr1 = __builtin_fmaf(zr, zr, t0);
  float zi1 = __builtin_fmaf(zr + zr, zi, ci);
  float m1  = __builtin_fmaf(zr1, zr1, zi1 * zi1);
  float t1  = __builtin_fmaf(-zi1, zi1, cr);
  float zr2 = __builtin_fmaf(zr1, zr1, t1);
  float zi2 = __builtin_fmaf(zr1 + zr1, zi1, ci);
  float m2  = __builtin_fmaf(zr2, zr2, zi2 * zi2);
  float t2  = __builtin_fmaf(-zi2, zi2, cr);
  float zr3 = __builtin_fmaf(zr2, zr2, t2);
  float zi3 = __builtin_fmaf(zr2 + zr2, zi2, ci);
  float m3  = __builtin_fmaf(zr3, zr3, zi3 * zi3);
  float t3  = __builtin_fmaf(-zi3, zi3, cr);
  float zr4 = __builtin_fmaf(zr3, zr3, t3);
  float zi4 = __builtin_fmaf(zr3 + zr3, zi3, ci);
  float m4  = __builtin_fmaf(zr4, zr4, zi4 * zi4);
  bool cyc  = (fabsf(zr4 - zr3) < EPS) & (fabsf(zi4 - zi3) < EPS);
  float f = 100.0f;                       // cycle (incl. cycle-beats-e4)
  if ((m4 > 4.0f) & (!cyc)) f = fb + 4.0f;
  if (m3 > 4.0f) f = fb + 3.0f;
  if (m2 > 4.0f) f = fb + 2.0f;
  if (m1 > 4.0f) f = fb + 1.0f;
  return fminf(f, 100.0f);                // last-round overshoot clamp
}

// Four packed Mandelbrot iterations on a 2-element pack; deferred escape
// check (monotone-growth soundness proven in round 6/8 header), cycle check
// once at step 4. Rare retire path replays scalar from entry state.
__device__ __forceinline__ void body4_pk(f32x2& zr, f32x2& zi, f32x2 cr, f32x2 ci,
                                         float fb, float& nd, bool& aX, bool& aY) {
  const f32x2 zr0 = zr, zi0 = zi;
  f32x2 t0  = pkfma(-zi, zi, cr);
  f32x2 zr1 = pkfma(zr, zr, t0);
  f32x2 zi1 = pkfma(zr + zr, zi, ci);
  f32x2 t1  = pkfma(-zi1, zi1, cr);
  f32x2 zr2 = pkfma(zr1, zr1, t1);
  f32x2 zi2 = pkfma(zr1 + zr1, zi1, ci);
  f32x2 t2  = pkfma(-zi2, zi2, cr);
  f32x2 zr3 = pkfma(zr2, zr2, t2);
  f32x2 zi3 = pkfma(zr2 + zr2, zi2, ci);
  f32x2 t3  = pkfma(-zi3, zi3, cr);
  f32x2 zr4 = pkfma(zr3, zr3, t3);
  f32x2 zi4 = pkfma(zr3 + zr3, zi3, ci);
  f32x2 mag = pkfma(zr4, zr4, zi4 * zi4);
  f32x2 dr  = zr4 - zr3;
  f32x2 di  = zi4 - zi3;
  zr = zr4; zi = zi4;
  bool hitX = ((mag[0] > 4.0f) | ((fabsf(dr[0]) < EPS) & (fabsf(di[0]) < EPS))) & aX;
  bool hitY = ((mag[1] > 4.0f) | ((fabsf(dr[1]) < EPS) & (fabsf(di[1]) < EPS))) & aY;
  if (hitX | hitY) {                       // rare path
    if (hitX) { nd += fabsf(decode4(zr0[0], zi0[0], cr[0], ci[0], fb) - TARGET) * INV_T; aX = false; }
    if (hitY) { nd += fabsf(decode4(zr0[1], zi0[1], cr[1], ci[1], fb) - TARGET) * INV_T; aY = false; }
  }
}

// Closed-form bounded-orbit test: main cardioid + period-2 bulb (=> exactly 100).
__device__ __forceinline__ bool inside_main_regions(float cr, float ci) {
  float ci2 = ci * ci;
  float xq  = cr - 0.25f;
  float q   = __builtin_fmaf(xq, xq, ci2);
  bool card = q * (q + xq) < 0.25f * ci2;
  float xb  = cr + 1.0f;
  bool bulb = __builtin_fmaf(xb, xb, ci2) < 0.0625f;
  return card | bulb;
}

__global__ __launch_bounds__(TPB) void escape_partial(
    const float* __restrict__ crg, const float* __restrict__ cig,
    float* __restrict__ partial, int n) {
  __shared__ float4 q[EPB];
  __shared__ int scount;
  __shared__ float sm[4];

  const int tid  = threadIdx.x;
  const int lane = tid & 63;
  const int wid  = tid >> 6;
  const int blockBase = blockIdx.x * EPB;

  float nd = 0.0f;

  // ---- phase A: iters 1..R0 from z=0, float4 global loads, 2 packs ----
  const bool fullBlock = (blockBase + EPB) <= n;
  float4 vcr, vci;
  if (fullBlock) {
    vcr = reinterpret_cast<const float4*>(crg + blockBase)[tid];
    vci = reinterpret_cast<const float4*>(cig + blockBase)[tid];
  } else {
    int b = blockBase + 4 * tid;
    vcr.x = (b + 0 < n) ? crg[b + 0] : 9.0f;  vci.x = (b + 0 < n) ? cig[b + 0] : 9.0f;
    vcr.y = (b + 1 < n) ? crg[b + 1] : 9.0f;  vci.y = (b + 1 < n) ? cig[b + 1] : 9.0f;
    vcr.z = (b + 2 < n) ? crg[b + 2] : 9.0f;  vci.z = (b + 2 < n) ? cig[b + 2] : 9.0f;
    vcr.w = (b + 3 < n) ? crg[b + 3] : 9.0f;  vci.w = (b + 3 < n) ? cig[b + 3] : 9.0f;
  }
  const bool vld0 = fullBlock || (blockBase + 4 * tid + 0 < n);
  const bool vld1 = fullBlock || (blockBase + 4 * tid + 1 < n);
  const bool vld2 = fullBlock || (blockBase + 4 * tid + 2 < n);
  const bool vld3 = fullBlock || (blockBase + 4 * tid + 3 < n);

  bool in0 = inside_main_regions(vcr.x, vci.x) & vld0;
  bool in1 = inside_main_regions(vcr.y, vci.y) & vld1;
  bool in2 = inside_main_regions(vcr.z, vci.z) & vld2;
  bool in3 = inside_main_regions(vcr.w, vci.w) & vld3;
  nd += (float)((int)in0 + (int)in1 + (int)in2 + (int)in3) * ND_INSET;

  bool a0 = vld0 & (!in0), a1 = vld1 & (!in1), a2 = vld2 & (!in2), a3 = vld3 & (!in3);
  f32x2 crP0 = {vcr.x, vcr.y}, ciP0 = {vci.x, vci.y};
  f32x2 crP1 = {vcr.z, vcr.w}, ciP1 = {vci.z, vci.w};
  f32x2 zrP0 = {0.0f, 0.0f}, ziP0 = {0.0f, 0.0f};
  f32x2 zrP1 = {0.0f, 0.0f}, ziP1 = {0.0f, 0.0f};

  body4_pk(zrP0, ziP0, crP0, ciP0, 0.0f, nd, a0, a1);
  body4_pk(zrP0, ziP0, crP0, ciP0, 4.0f, nd, a0, a1);
  body4_pk(zrP0, ziP0, crP0, ciP0, 8.0f, nd, a0, a1);
  body4_pk(zrP1, ziP1, crP1, ciP1, 0.0f, nd, a2, a3);
  body4_pk(zrP1, ziP1, crP1, ciP1, 4.0f, nd, a2, a3);
  body4_pk(zrP1, ziP1, crP1, ciP1, 8.0f, nd, a2, a3);

  {
    const float eZr[4] = {zrP0[0], zrP0[1], zrP1[0], zrP1[1]};
    const float eZi[4] = {ziP0[0], ziP0[1], ziP1[0], ziP1[1]};
    const float eCr[4] = {vcr.x, vcr.y, vcr.z, vcr.w};
    const float eCi[4] = {vci.x, vci.y, vci.z, vci.w};
    const bool  eAl[4] = {a0, a1, a2, a3};
    if (tid == 0) scount = 0;
    __syncthreads();
    #pragma unroll
    for (int k = 0; k < 4; ++k) {          // ballot-compact append into LDS queue
      unsigned long long bal = __ballot(eAl[k]);
      int cnt = __popcll(bal);
      if (cnt) {
        int wbase = 0;
        if (lane == 0) wbase = atomicAdd(&scount, cnt);
        wbase = __shfl(wbase, 0, 64);
        if (eAl[k]) {
          int pos = wbase + __popcll(bal & ((1ull << lane) - 1ull));
          q[pos] = make_float4(eZr[k], eZi[k], eCr[k], eCi[k]);
        }
      }
    }
  }
  __syncthreads();
  int S = scount;
  int rot = 0;

  // ---- queue rounds: base = 12,24,...,96 (last overshoots to 108; clamped) ----
  // Pack layout: pack0 = entries (2e, 2e+1), pack1 = (512+2e, 513+2e) —
  // consecutive entries so dead waves still whole-wave skip as S shrinks.
  for (int base = R0; base < MAXIT && S > 0; base += RSTEP) {
    rot = (rot + 64) & (TPB - 1);          // rotate partial-wave tail across SIMDs
    const int effTid = (tid + rot) & (TPB - 1);
    const float fb = (float)base;
    const int j0 = 2 * effTid, j1 = j0 + 1;
    const int j2 = 512 + 2 * effTid, j3 = j2 + 1;
    bool a0q = j0 < S, a1q = j1 < S, a2q = j2 < S, a3q = j3 < S;
    float4 e0 = q[a0q ? j0 : 0];
    float4 e1 = q[a1q ? j1 : 0];
    float4 e2 = q[a2q ? j2 : 0];
    float4 e3 = q[a3q ? j3 : 0];
    f32x2 zr0q = {e0.x, e1.x}, zi0q = {e0.y, e1.y};
    f32x2 cr0q = {e0.z, e1.z}, ci0q = {e0.w, e1.w};
    f32x2 zr1q = {e2.x, e3.x}, zi1q = {e2.y, e3.y};
    f32x2 cr1q = {e2.z, e3.z}, ci1q = {e2.w, e3.w};

    if (a0q) {                             // whole pack0 dead => skip (wave-coherent)
      body4_pk(zr0q, zi0q, cr0q, ci0q, fb,        nd, a0q, a1q);
      body4_pk(zr0q, zi0q, cr0q, ci0q, fb + 4.0f, nd, a0q, a1q);
      body4_pk(zr0q, zi0q, cr0q, ci0q, fb + 8.0f, nd, a0q, a1q);
    }
    if (a2q) {
      body4_pk(zr1q, zi1q, cr1q, ci1q, fb,        nd, a2q, a3q);
      body4_pk(zr1q, zi1q, cr1q, ci1q, fb + 4.0f, nd, a2q, a3q);
      body4_pk(zr1q, zi1q, cr1q, ci1q, fb + 8.0f, nd, a2q, a3q);
    }

    __syncthreads();                       // all queue reads done
    if (tid == 0) scount = 0;
    __syncthreads();
    {
      const float eZr[4] = {zr0q[0], zr0q[1], zr1q[0], zr1q[1]};
      const float eZi[4] = {zi0q[0], zi0q[1], zi1q[0], zi1q[1]};
      const float eCr[4] = {cr0q[0], cr0q[1], cr1q[0], cr1q[1]};
      const float eCi[4] = {ci0q[0], ci0q[1], ci1q[0], ci1q[1]};
      const bool  eAl[4] = {a0q, a1q, a2q, a3q};
      #pragma unroll
      for (int k = 0; k < 4; ++k) {        // in-place re-compaction
        unsigned long long bal = __ballot(eAl[k]);
        int cnt = __popcll(bal);
        if (cnt) {
          int wbase = 0;
          if (lane == 0) wbase = atomicAdd(&scount, cnt);
          wbase = __shfl(wbase, 0, 64);
          if (eAl[k]) {
            int pos = wbase + __popcll(bal & ((1ull << lane) - 1ull));
            q[pos] = make_float4(eZr[k], eZi[k], eCr[k], eCi[k]);
          }
        }
      }
    }
    __syncthreads();
    S = scount;
  }

  // ---- survivors (ran to >=100 without escape/cycle): iters = 100 ----
  {
    int mine = (int)(2 * tid < S) + (int)(2 * tid + 1 < S)
             + (int)(512 + 2 * tid < S) + (int)(513 + 2 * tid < S);
    nd += (float)mine * ND_INSET;
  }

  // ---- block reduce ----
  for (int off = 32; off > 0; off >>= 1) nd += __shfl_down(nd, off, 64);
  if (lane == 0) sm[wid] = nd;
  __syncthreads();
  if (tid == 0) partial[blockIdx.x] = sm[0] + sm[1] + sm[2] + sm[3];
}

// Single block, float4 reads of the partials.
__global__ __launch_bounds__(256) void reduce_final(
    const float* __restrict__ partial, int nparts,
    float* __restrict__ out, float scale) {
  float s = 0.0f;
  int n4 = nparts >> 2;
  const float4* p4 = reinterpret_cast<const float4*>(partial);
  for (int i = threadIdx.x; i < n4; i += 256) {
    float4 v = p4[i];
    s += (v.x + v.y) + (v.z + v.w);
  }
  for (int i = (n4 << 2) + threadIdx.x; i < nparts; i += 256) s += partial[i];
  for (int off = 32; off > 0; off >>= 1) s += __shfl_down(s, off, 64);
  __shared__ float sm[4];
  int lane = threadIdx.x & 63, wid = threadIdx.x >> 6;
  if (lane == 0) sm[wid] = s;
  __syncthreads();
  if (threadIdx.x == 0)
    out[0] = (sm[0] + sm[1] + sm[2] + sm[3]) * scale;
}

extern "C" void kernel_launch(void* const* d_in, const int* in_sizes, int n_in,
                              void* d_out, int out_size, void* d_ws, size_t ws_size,
                              hipStream_t stream) {
  const float* cr = (const float*)d_in[0];
  const float* ci = (const float*)d_in[1];
  int n = in_sizes[0];
  int blocks = (n + EPB - 1) / EPB;        // 8192 at N=8388608
  float* partial = (float*)d_ws;

  escape_partial<<<blocks, TPB, 0, stream>>>(cr, ci, partial, n);
  reduce_final<<<1, 256, 0, stream>>>(partial, blocks, (float*)d_out,
                                      WEIGHT / (float)n);
}

// Round 11
// 134.098 us; speedup vs baseline: 1.2449x; 1.2449x over previous
//
#include <hip/hip_runtime.h>

#define MAXIT  100
#define TARGET 30.0f
#define WEIGHT 0.1f
#define EPB    1024    // elements per block
#define TPB    256
#define R0     12      // phase-A iters (3 bodies of 4, from z=0)
#define RSTEP  12      // iters per queue round (3 bodies of 4)
#define ND_INSET ((100.0f - TARGET) * (1.0f / TARGET))
#define INV_T  (1.0f / TARGET)

// Four Mandelbrot iterations with DEFERRED escape check (tested once, at the
// 4th step). Soundness: entering mag <= 4 and |c| <= 2 for any orbit that
// reaches here (|c| > 2 escapes at iter 1 = body4 #1 step 1, where growth is
// also monotone); once mag_j > 4, |z_{j+1}| >= mag_j - |c| > sqrt(mag_j), so
// mag grows monotonically and m4 > 4 catches any in-body escape. Exact escape
// step decoded in the rare retire path from live intermediates.
//
// NO cycle check: the reference's 1-step cycle detector always records 100.0
// — identical to running out the loop. It only matters for (a) period-1
// convergents = cardioid interior, removed analytically below (they'd just
// run out to 100 here, same value), and (b) near-repelling-fixed-point
// "lingerers" (step < 1e-6 then escape), a <=1e-6-measure band contributing
// ~3.6e-8 to the scalar output vs threshold 2.35e-3 — the same error class
// as round 6/8's delayed detection, which benched absmax 0.0.
__device__ __forceinline__ void body4(float& zr, float& zi, float cr, float ci,
                                      float fb, float& nd, bool& alive) {
  float t0  = __builtin_fmaf(-zi, zi, cr);
  float zr1 = __builtin_fmaf(zr, zr, t0);
  float zi1 = __builtin_fmaf(zr + zr, zi, ci);

  float t1  = __builtin_fmaf(-zi1, zi1, cr);
  float zr2 = __builtin_fmaf(zr1, zr1, t1);
  float zi2 = __builtin_fmaf(zr1 + zr1, zi1, ci);

  float t2  = __builtin_fmaf(-zi2, zi2, cr);
  float zr3 = __builtin_fmaf(zr2, zr2, t2);
  float zi3 = __builtin_fmaf(zr2 + zr2, zi2, ci);

  float t3  = __builtin_fmaf(-zi3, zi3, cr);
  float zr4 = __builtin_fmaf(zr3, zr3, t3);
  float zi4 = __builtin_fmaf(zr3 + zr3, zi3, ci);

  float m4  = __builtin_fmaf(zr4, zr4, zi4 * zi4);
  zr = zr4; zi = zi4;

  if ((m4 > 4.0f) & alive) {                 // rare path: retire + decode
    bool e1 = __builtin_fmaf(zr1, zr1, zi1 * zi1) > 4.0f;
    bool e2 = __builtin_fmaf(zr2, zr2, zi2 * zi2) > 4.0f;
    bool e3 = __builtin_fmaf(zr3, zr3, zi3 * zi3) > 4.0f;
    float f = fb + 4.0f;
    if (e3) f = fb + 3.0f;
    if (e2) f = fb + 2.0f;
    if (e1) f = fb + 1.0f;
    f = fminf(f, 100.0f);                    // last-round overshoot clamp
    nd += fabsf(f - TARGET) * INV_T;
    alive = false;
  }
}

// Closed-form bounded-orbit test: main cardioid + period-2 bulb.
// For these c the reference provably outputs exactly 100.0.
__device__ __forceinline__ bool inside_main_regions(float cr, float ci) {
  float ci2 = ci * ci;
  float xq  = cr - 0.25f;
  float q   = __builtin_fmaf(xq, xq, ci2);
  bool card = q * (q + xq) < 0.25f * ci2;
  float xb  = cr + 1.0f;
  bool bulb = __builtin_fmaf(xb, xb, ci2) < 0.0625f;
  return card | bulb;
}

__global__ __launch_bounds__(TPB) void escape_partial(
    const float* __restrict__ crg, const float* __restrict__ cig,
    float* __restrict__ partial, int n) {
  __shared__ float4 q[EPB];
  __shared__ int scount;
  __shared__ float sm[4];

  const int tid  = threadIdx.x;
  const int lane = tid & 63;
  const int wid  = tid >> 6;
  const int blockBase = blockIdx.x * EPB;

  float nd = 0.0f;
  float eZr[4], eZi[4], eCr[4], eCi[4];
  bool  eAl[4];

  // ---- phase A: iters 1..R0 from z=0, float4 global loads ----
  const bool fullBlock = (blockBase + EPB) <= n;
  float4 vcr, vci;
  if (fullBlock) {
    vcr = reinterpret_cast<const float4*>(crg + blockBase)[tid];
    vci = reinterpret_cast<const float4*>(cig + blockBase)[tid];
  } else {
    int b = blockBase + 4 * tid;
    vcr.x = (b + 0 < n) ? crg[b + 0] : 9.0f;  vci.x = (b + 0 < n) ? cig[b + 0] : 9.0f;
    vcr.y = (b + 1 < n) ? crg[b + 1] : 9.0f;  vci.y = (b + 1 < n) ? cig[b + 1] : 9.0f;
    vcr.z = (b + 2 < n) ? crg[b + 2] : 9.0f;  vci.z = (b + 2 < n) ? cig[b + 2] : 9.0f;
    vcr.w = (b + 3 < n) ? crg[b + 3] : 9.0f;  vci.w = (b + 3 < n) ? cig[b + 3] : 9.0f;
  }
  const float crs[4] = {vcr.x, vcr.y, vcr.z, vcr.w};
  const float cis[4] = {vci.x, vci.y, vci.z, vci.w};
  const bool  vld[4] = {
    fullBlock || (blockBase + 4 * tid + 0 < n),
    fullBlock || (blockBase + 4 * tid + 1 < n),
    fullBlock || (blockBase + 4 * tid + 2 < n),
    fullBlock || (blockBase + 4 * tid + 3 < n)};

  #pragma unroll
  for (int k = 0; k < 4; ++k) {
    float c_r = crs[k], c_i = cis[k];
    bool inside = inside_main_regions(c_r, c_i) & vld[k];
    if (inside) nd += ND_INSET;            // provably iters == 100
    float zr = 0.0f, zi = 0.0f;            // body4 from z=0 reproduces z1=c
    bool alive = vld[k] & (!inside);
    body4(zr, zi, c_r, c_i, 0.0f, nd, alive);
    body4(zr, zi, c_r, c_i, 4.0f, nd, alive);
    body4(zr, zi, c_r, c_i, 8.0f, nd, alive);
    eAl[k] = alive; eZr[k] = zr; eZi[k] = zi; eCr[k] = c_r; eCi[k] = c_i;
  }

  if (tid == 0) scount = 0;
  __syncthreads();
  #pragma unroll
  for (int k = 0; k < 4; ++k) {            // ballot-compact append into LDS queue
    unsigned long long bal = __ballot(eAl[k]);
    int cnt = __popcll(bal);
    if (cnt) {
      int wbase = 0;
      if (lane == 0) wbase = atomicAdd(&scount, cnt);
      wbase = __shfl(wbase, 0, 64);
      if (eAl[k]) {
        int pos = wbase + __popcll(bal & ((1ull << lane) - 1ull));
        q[pos] = make_float4(eZr[k], eZi[k], eCr[k], eCi[k]);
      }
    }
  }
  __syncthreads();
  int S = scount;
  int rot = 0;

  // ---- queue rounds: base = 12,24,...,96 (last overshoots to 108; clamped) ----
  for (int base = R0; base < MAXIT && S > 0; base += RSTEP) {
    rot = (rot + 64) & (TPB - 1);          // rotate partial-wave tail across SIMDs
    const int effTid = (tid + rot) & (TPB - 1);
    const float fb = (float)base;
    #pragma unroll
    for (int k = 0; k < 4; ++k) {
      eAl[k] = false;
      int j = k * TPB + effTid;
      if (j < S) {
        float4 e = q[j];
        float zr = e.x, zi = e.y, c_r = e.z, c_i = e.w;
        bool alive = true;
        body4(zr, zi, c_r, c_i, fb, nd, alive);
        body4(zr, zi, c_r, c_i, fb + 4.0f, nd, alive);
        body4(zr, zi, c_r, c_i, fb + 8.0f, nd, alive);
        eAl[k] = alive; eZr[k] = zr; eZi[k] = zi; eCr[k] = c_r; eCi[k] = c_i;
      }
    }
    __syncthreads();                       // all queue reads done
    if (tid == 0) scount = 0;
    __syncthreads();
    #pragma unroll
    for (int k = 0; k < 4; ++k) {          // in-place re-compaction
      unsigned long long bal = __ballot(eAl[k]);
      int cnt = __popcll(bal);
      if (cnt) {
        int wbase = 0;
        if (lane == 0) wbase = atomicAdd(&scount, cnt);
        wbase = __shfl(wbase, 0, 64);
        if (eAl[k]) {
          int pos = wbase + __popcll(bal & ((1ull << lane) - 1ull));
          q[pos] = make_float4(eZr[k], eZi[k], eCr[k], eCi[k]);
        }
      }
    }
    __syncthreads();
    S = scount;
  }

  // ---- survivors (never escaped within 100 iters): iters = 100 ----
  {
    int mine = 0;
    #pragma unroll
    for (int k = 0; k < 4; ++k) if (k * TPB + tid < S) ++mine;
    nd += (float)mine * ND_INSET;
  }

  // ---- block reduce ----
  for (int off = 32; off > 0; off >>= 1) nd += __shfl_down(nd, off, 64);
  if (lane == 0) sm[wid] = nd;
  __syncthreads();
  if (tid == 0) partial[blockIdx.x] = sm[0] + sm[1] + sm[2] + sm[3];
}

// Single block, float4 reads of the partials.
__global__ __launch_bounds__(256) void reduce_final(
    const float* __restrict__ partial, int nparts,
    float* __restrict__ out, float scale) {
  float s = 0.0f;
  int n4 = nparts >> 2;
  const float4* p4 = reinterpret_cast<const float4*>(partial);
  for (int i = threadIdx.x; i < n4; i += 256) {
    float4 v = p4[i];
    s += (v.x + v.y) + (v.z + v.w);
  }
  for (int i = (n4 << 2) + threadIdx.x; i < nparts; i += 256) s += partial[i];
  for (int off = 32; off > 0; off >>= 1) s += __shfl_down(s, off, 64);
  __shared__ float sm[4];
  int lane = threadIdx.x & 63, wid = threadIdx.x >> 6;
  if (lane == 0) sm[wid] = s;
  __syncthreads();
  if (threadIdx.x == 0)
    out[0] = (sm[0] + sm[1] + sm[2] + sm[3]) * scale;
}

extern "C" void kernel_launch(void* const* d_in, const int* in_sizes, int n_in,
                              void* d_out, int out_size, void* d_ws, size_t ws_size,
                              hipStream_t stream) {
  const float* cr = (const float*)d_in[0];
  const float* ci = (const float*)d_in[1];
  int n = in_sizes[0];
  int blocks = (n + EPB - 1) / EPB;        // 8192 at N=8388608
  float* partial = (float*)d_ws;

  escape_partial<<<blocks, TPB, 0, stream>>>(cr, ci, partial, n);
  reduce_final<<<1, 256, 0, stream>>>(partial, blocks, (float*)d_out,
                                      WEIGHT / (float)n);
}

// Round 12
// 122.058 us; speedup vs baseline: 1.3677x; 1.0986x over previous
//
#include <hip/hip_runtime.h>

#define MAXIT  100
#define TARGET 30.0f
#define WEIGHT 0.1f
#define EPB    1024    // elements per block
#define TPB    256
#define R0     4       // phase-A iters (1 body of 4, from z=0)
#define RSTEP  16      // iters per queue round (4 bodies of 4); 4+16*6 = 100 exact
#define ND_INSET ((100.0f - TARGET) * (1.0f / TARGET))
#define INV_T  (1.0f / TARGET)

// Four Mandelbrot iterations with DEFERRED escape check (tested once, at the
// 4th step). Soundness: entering mag <= 4 and |c| <= 2 for any orbit that
// reaches here (|c| > 2 escapes at iter 1 = body4 #1 step 1, where growth is
// also monotone); once mag_j > 4, |z_{j+1}| >= mag_j - |c| > sqrt(mag_j), so
// mag grows monotonically and m4 > 4 catches any in-body escape. Exact escape
// step decoded in the rare retire path from live intermediates.
//
// NO cycle check: the reference's 1-step cycle detector always records 100.0
// — identical to running out the loop. Period-1 convergents (the only ones a
// 1-step detector catches) are the cardioid interior, retired analytically;
// the residual "lingerer" band (step < 1e-6 then escape) contributes ~3.6e-8
// to the scalar output vs threshold 2.35e-3 (benched absmax 0.0, rounds 8/11).
__device__ __forceinline__ void body4(float& zr, float& zi, float cr, float ci,
                                      float fb, float& nd, bool& alive) {
  float t0  = __builtin_fmaf(-zi, zi, cr);
  float zr1 = __builtin_fmaf(zr, zr, t0);
  float zi1 = __builtin_fmaf(zr + zr, zi, ci);

  float t1  = __builtin_fmaf(-zi1, zi1, cr);
  float zr2 = __builtin_fmaf(zr1, zr1, t1);
  float zi2 = __builtin_fmaf(zr1 + zr1, zi1, ci);

  float t2  = __builtin_fmaf(-zi2, zi2, cr);
  float zr3 = __builtin_fmaf(zr2, zr2, t2);
  float zi3 = __builtin_fmaf(zr2 + zr2, zi2, ci);

  float t3  = __builtin_fmaf(-zi3, zi3, cr);
  float zr4 = __builtin_fmaf(zr3, zr3, t3);
  float zi4 = __builtin_fmaf(zr3 + zr3, zi3, ci);

  float m4  = __builtin_fmaf(zr4, zr4, zi4 * zi4);
  zr = zr4; zi = zi4;

  if ((m4 > 4.0f) & alive) {                 // rare path: retire + decode
    bool e1 = __builtin_fmaf(zr1, zr1, zi1 * zi1) > 4.0f;
    bool e2 = __builtin_fmaf(zr2, zr2, zi2 * zi2) > 4.0f;
    bool e3 = __builtin_fmaf(zr3, zr3, zi3 * zi3) > 4.0f;
    float f = fb + 4.0f;
    if (e3) f = fb + 3.0f;
    if (e2) f = fb + 2.0f;
    if (e1) f = fb + 1.0f;
    f = fminf(f, 100.0f);                    // safety clamp (no overshoot at RSTEP=16)
    nd += fabsf(f - TARGET) * INV_T;
    alive = false;
  }
}

// Closed-form bounded-orbit test: main cardioid + period-2 bulb.
// For these c the reference provably outputs exactly 100.0.
__device__ __forceinline__ bool inside_main_regions(float cr, float ci) {
  float ci2 = ci * ci;
  float xq  = cr - 0.25f;
  float q   = __builtin_fmaf(xq, xq, ci2);
  bool card = q * (q + xq) < 0.25f * ci2;
  float xb  = cr + 1.0f;
  bool bulb = __builtin_fmaf(xb, xb, ci2) < 0.0625f;
  return card | bulb;
}

__global__ __launch_bounds__(TPB) void escape_partial(
    const float* __restrict__ crg, const float* __restrict__ cig,
    float* __restrict__ partial, int n) {
  __shared__ float4 q[EPB];
  __shared__ int scount;
  __shared__ float sm[4];

  const int tid  = threadIdx.x;
  const int lane = tid & 63;
  const int wid  = tid >> 6;
  const int blockBase = blockIdx.x * EPB;

  float nd = 0.0f;
  float eZr[4], eZi[4], eCr[4], eCi[4];
  bool  eAl[4];

  // ---- phase A: iters 1..4 from z=0, float4 global loads ----
  const bool fullBlock = (blockBase + EPB) <= n;
  float4 vcr, vci;
  if (fullBlock) {
    vcr = reinterpret_cast<const float4*>(crg + blockBase)[tid];
    vci = reinterpret_cast<const float4*>(cig + blockBase)[tid];
  } else {
    int b = blockBase + 4 * tid;
    vcr.x = (b + 0 < n) ? crg[b + 0] : 9.0f;  vci.x = (b + 0 < n) ? cig[b + 0] : 9.0f;
    vcr.y = (b + 1 < n) ? crg[b + 1] : 9.0f;  vci.y = (b + 1 < n) ? cig[b + 1] : 9.0f;
    vcr.z = (b + 2 < n) ? crg[b + 2] : 9.0f;  vci.z = (b + 2 < n) ? cig[b + 2] : 9.0f;
    vcr.w = (b + 3 < n) ? crg[b + 3] : 9.0f;  vci.w = (b + 3 < n) ? cig[b + 3] : 9.0f;
  }
  const float crs[4] = {vcr.x, vcr.y, vcr.z, vcr.w};
  const float cis[4] = {vci.x, vci.y, vci.z, vci.w};
  const bool  vld[4] = {
    fullBlock || (blockBase + 4 * tid + 0 < n),
    fullBlock || (blockBase + 4 * tid + 1 < n),
    fullBlock || (blockBase + 4 * tid + 2 < n),
    fullBlock || (blockBase + 4 * tid + 3 < n)};

  #pragma unroll
  for (int k = 0; k < 4; ++k) {
    float c_r = crs[k], c_i = cis[k];
    bool inside = inside_main_regions(c_r, c_i) & vld[k];
    if (inside) nd += ND_INSET;            // provably iters == 100
    float zr = 0.0f, zi = 0.0f;            // body4 from z=0 reproduces z1=c
    bool alive = vld[k] & (!inside);
    body4(zr, zi, c_r, c_i, 0.0f, nd, alive);
    eAl[k] = alive; eZr[k] = zr; eZi[k] = zi; eCr[k] = c_r; eCi[k] = c_i;
  }

  if (tid == 0) scount = 0;
  __syncthreads();
  #pragma unroll
  for (int k = 0; k < 4; ++k) {            // ballot-compact append into LDS queue
    unsigned long long bal = __ballot(eAl[k]);
    int cnt = __popcll(bal);
    if (cnt) {
      int wbase = 0;
      if (lane == 0) wbase = atomicAdd(&scount, cnt);
      wbase = __shfl(wbase, 0, 64);
      if (eAl[k]) {
        int pos = wbase + __popcll(bal & ((1ull << lane) - 1ull));
        q[pos] = make_float4(eZr[k], eZi[k], eCr[k], eCi[k]);
      }
    }
  }
  __syncthreads();
  int S = scount;
  int rot = 0;

  // ---- queue rounds: base = 4,20,36,52,68,84 (each 16 iters; ends at 100) ----
  for (int base = R0; base < MAXIT && S > 0; base += RSTEP) {
    rot = (rot + 64) & (TPB - 1);          // rotate partial-wave tail across SIMDs
    const int effTid = (tid + rot) & (TPB - 1);
    const float fb = (float)base;
    #pragma unroll
    for (int k = 0; k < 4; ++k) {
      eAl[k] = false;
      int j = k * TPB + effTid;
      if (j < S) {
        float4 e = q[j];
        float zr = e.x, zi = e.y, c_r = e.z, c_i = e.w;
        bool alive = true;
        body4(zr, zi, c_r, c_i, fb,         nd, alive);
        body4(zr, zi, c_r, c_i, fb +  4.0f, nd, alive);
        body4(zr, zi, c_r, c_i, fb +  8.0f, nd, alive);
        body4(zr, zi, c_r, c_i, fb + 12.0f, nd, alive);
        eAl[k] = alive; eZr[k] = zr; eZi[k] = zi; eCr[k] = c_r; eCi[k] = c_i;
      }
    }
    __syncthreads();                       // all queue reads done
    if (tid == 0) scount = 0;
    __syncthreads();
    #pragma unroll
    for (int k = 0; k < 4; ++k) {          // in-place re-compaction
      unsigned long long bal = __ballot(eAl[k]);
      int cnt = __popcll(bal);
      if (cnt) {
        int wbase = 0;
        if (lane == 0) wbase = atomicAdd(&scount, cnt);
        wbase = __shfl(wbase, 0, 64);
        if (eAl[k]) {
          int pos = wbase + __popcll(bal & ((1ull << lane) - 1ull));
          q[pos] = make_float4(eZr[k], eZi[k], eCr[k], eCi[k]);
        }
      }
    }
    __syncthreads();
    S = scount;
  }

  // ---- survivors (never escaped within 100 iters): iters = 100 ----
  {
    int mine = 0;
    #pragma unroll
    for (int k = 0; k < 4; ++k) if (k * TPB + tid < S) ++mine;
    nd += (float)mine * ND_INSET;
  }

  // ---- block reduce ----
  for (int off = 32; off > 0; off >>= 1) nd += __shfl_down(nd, off, 64);
  if (lane == 0) sm[wid] = nd;
  __syncthreads();
  if (tid == 0) partial[blockIdx.x] = sm[0] + sm[1] + sm[2] + sm[3];
}

// Single block, float4 reads of the partials.
__global__ __launch_bounds__(256) void reduce_final(
    const float* __restrict__ partial, int nparts,
    float* __restrict__ out, float scale) {
  float s = 0.0f;
  int n4 = nparts >> 2;
  const float4* p4 = reinterpret_cast<const float4*>(partial);
  for (int i = threadIdx.x; i < n4; i += 256) {
    float4 v = p4[i];
    s += (v.x + v.y) + (v.z + v.w);
  }
  for (int i = (n4 << 2) + threadIdx.x; i < nparts; i += 256) s += partial[i];
  for (int off = 32; off > 0; off >>= 1) s += __shfl_down(s, off, 64);
  __shared__ float sm[4];
  int lane = threadIdx.x & 63, wid = threadIdx.x >> 6;
  if (lane == 0) sm[wid] = s;
  __syncthreads();
  if (threadIdx.x == 0)
    out[0] = (sm[0] + sm[1] + sm[2] + sm[3]) * scale;
}

extern "C" void kernel_launch(void* const* d_in, const int* in_sizes, int n_in,
                              void* d_out, int out_size, void* d_ws, size_t ws_size,
                              hipStream_t stream) {
  const float* cr = (const float*)d_in[0];
  const float* ci = (const float*)d_in[1];
  int n = in_sizes[0];
  int blocks = (n + EPB - 1) / EPB;        // 8192 at N=8388608
  float* partial = (float*)d_ws;

  escape_partial<<<blocks, TPB, 0, stream>>>(cr, ci, partial, n);
  reduce_final<<<1, 256, 0, stream>>>(partial, blocks, (float*)d_out,
                                      WEIGHT / (float)n);
}